// Round 1
// 232.763 us; speedup vs baseline: 1.0118x; 1.0118x over previous
//
#include <hip/hip_runtime.h>

#define BB 64
#define CC 128
#define TT 4096
#define NN 6            // KNOT + 2
#define HH 819.0f       // (T-1)/(KNOT+1) = 4095/5, exact in fp32
#define NTHR 512
#define EPT 8           // curve elements per thread (NTHR*EPT == TT)

__global__ __launch_bounds__(NTHR) void timewarp_kernel(
    const float* __restrict__ x,
    const float* __restrict__ yy,
    const float* __restrict__ mask_rand,
    float* __restrict__ out)
{
    const int row = blockIdx.x;          // b*C + c
    const int b   = row / CC;
    const int c   = row % CC;
    const int tid = threadIdx.x;

    const float* xrow = x + (size_t)row * TT;
    float* orow       = out + (size_t)row * TT;

    // mask_rand >= 0.5 -> bit-exact copy (uniform per block)
    if (!(mask_rand[b] < 0.5f)) {
        const float4* xi = (const float4*)xrow;
        float4* oo = (float4*)orow;
        oo[tid]        = xi[tid];
        oo[tid + NTHR] = xi[tid + NTHR];
        return;
    }

    __shared__ float sh_xp[TT];          // warped positions, canonical copy
    __shared__ float sh_fp[TT];          // x row staged for gather
    __shared__ float sh_wsum[NTHR / 64]; // per-wave scan totals

    // ---- coalesced load of x (lane-contiguous float4, 1 KiB/wave/instr) ----
    const float4 xv0 = ((const float4*)xrow)[tid];
    const float4 xv1 = ((const float4*)xrow)[tid + NTHR];

    // ---- 6x6 not-a-knot solve, redundantly on every thread ----
    // A is compile-time constant -> elimination multipliers fold to constants;
    // yy addresses are block-uniform -> scalar loads. No barrier needed.
    float Mv[NN];
    float y[NN];
    {
        #pragma unroll
        for (int k = 0; k < NN; ++k)
            y[k] = yy[((size_t)b * NN + k) * CC + c];
        float Aug[NN][NN + 1];
        #pragma unroll
        for (int i = 0; i < NN; ++i)
            #pragma unroll
            for (int j = 0; j < NN + 1; ++j)
                Aug[i][j] = 0.0f;
        Aug[0][0] = 1.0f;  Aug[0][1] = -2.0f;  Aug[0][2] = 1.0f;
        Aug[5][3] = 1.0f;  Aug[5][4] = -2.0f;  Aug[5][5] = 1.0f;
        #pragma unroll
        for (int i = 1; i < NN - 1; ++i) {
            Aug[i][i - 1] = HH / 6.0f;
            Aug[i][i]     = 2.0f * HH / 3.0f;
            Aug[i][i + 1] = HH / 6.0f;
            Aug[i][NN]    = (y[i + 1] - 2.0f * y[i] + y[i - 1]) / HH;
        }
        #pragma unroll
        for (int k = 0; k < NN; ++k) {
            float inv = 1.0f / Aug[k][k];
            #pragma unroll
            for (int i = k + 1; i < NN; ++i) {
                float m = Aug[i][k] * inv;
                #pragma unroll
                for (int j = k; j < NN + 1; ++j)
                    Aug[i][j] -= m * Aug[k][j];
            }
        }
        #pragma unroll
        for (int i = NN - 1; i >= 0; --i) {
            float s = Aug[i][NN];
            #pragma unroll
            for (int j = i + 1; j < NN; ++j)
                s -= Aug[i][j] * Mv[j];
            Mv[i] = s / Aug[i][i];
        }
    }

    // ---- per-thread span coefficient sets (STATIC indexing only) ----
    // This thread's 8 consecutive t's cross at most one knot boundary
    // (span length 819 >> 8). Pre-select sets A (span idxA) and B (idxA+1,
    // clamped). All Mv/y accesses below have compile-time indices ->
    // cndmask chains, no dynamic register indexing, no scratch.
    const int t0 = tid * EPT;
    int idxA = t0 / 819;  if (idxA > 4) idxA = 4;
    int idxB = idxA + 1;  if (idxB > 4) idxB = 4;
    float MiA = Mv[0], Mi1A = Mv[1], yiA = y[0], yi1A = y[1];
    #pragma unroll
    for (int s = 1; s <= 4; ++s)
        if (idxA >= s) { MiA = Mv[s]; Mi1A = Mv[s + 1]; yiA = y[s]; yi1A = y[s + 1]; }
    float MiB = Mv[0], Mi1B = Mv[1], yiB = y[0], yi1B = y[1];
    #pragma unroll
    for (int s = 1; s <= 4; ++s)
        if (idxB >= s) { MiB = Mv[s]; Mi1B = Mv[s + 1]; yiB = y[s]; yi1B = y[s + 1]; }
    const float tb  = (float)((idxA + 1) * 819);   // first t in span B
    const float xlA = (float)idxA * HH;
    const float xlB = (float)idxB * HH;

    // ---- curve + thread-local inclusive scan ----
    const float inv6h = 1.0f / (6.0f * HH);
    const float hd6   = HH / 6.0f;
    const float invh  = 1.0f / HH;
    float loc[EPT];
    float running = 0.0f;
    #pragma unroll
    for (int k = 0; k < EPT; ++k) {
        float ft  = (float)(t0 + k);
        bool  inB = ft >= tb;
        float Mi  = inB ? MiB  : MiA;
        float Mi1 = inB ? Mi1B : Mi1A;
        float yi  = inB ? yiB  : yiA;
        float yi1 = inB ? yi1B : yi1A;
        float xl  = inB ? xlB  : xlA;
        float dxl = ft - xl;
        float dxr = xl + HH - ft;
        float curve = (Mi * dxr * dxr * dxr + Mi1 * dxl * dxl * dxl) * inv6h
                    + (yi * invh - Mi * hd6) * dxr
                    + (yi1 * invh - Mi1 * hd6) * dxl;
        running += curve;
        loc[k] = running;
    }

    // stash fp into LDS (fenced by the barrier before gather)
    ((float4*)sh_fp)[tid]        = xv0;
    ((float4*)sh_fp)[tid + NTHR] = xv1;

    // ---- wave scan (shfl) + cross-wave fixup (barrier 1) ----
    const int lane = tid & 63, wid = tid >> 6;
    float ws = running;
    #pragma unroll
    for (int d = 1; d < 64; d <<= 1) {
        float v = __shfl_up(ws, d, 64);
        if (lane >= d) ws += v;
    }
    if (lane == 63) sh_wsum[wid] = ws;
    __syncthreads();
    float wo = 0.0f, total = 0.0f;
    #pragma unroll
    for (int w = 0; w < NTHR / 64; ++w) {
        float s = sh_wsum[w];
        total += s;
        if (w < wid) wo += s;
    }
    const float offs  = wo + (ws - running);   // exclusive prefix of this thread
    const float scale = 4095.0f / total;       // tt * (T-1) / tt_last

    // ---- xp -> LDS (canonical copy; no cross-thread consistency hazard) ----
    {
        float4 a, bq;
        a.x  = (loc[0] + offs) * scale;  a.y  = (loc[1] + offs) * scale;
        a.z  = (loc[2] + offs) * scale;  a.w  = (loc[3] + offs) * scale;
        bq.x = (loc[4] + offs) * scale;  bq.y = (loc[5] + offs) * scale;
        bq.z = (loc[6] + offs) * scale;  bq.w = (loc[7] + offs) * scale;
        ((float4*)(sh_xp + t0))[0] = a;
        ((float4*)(sh_xp + t0))[1] = bq;
    }
    __syncthreads();                           // barrier 2: xp + fp visible

    // ---- gather: 2 chunks of 4 consecutive outputs per thread ----
    // Branchless binary search (two independent chains for MLP), then a
    // short monotone walk across the 4 consecutive q's. Every output is
    // computed directly: uniform work, no coverage gaps possible.
    const int q0a = 4 * tid;
    const int q0b = 4 * (tid + NTHR);
    const float fq0a = (float)q0a;
    const float fq0b = (float)q0b;
    int j0 = -1, j1 = -1;
    #pragma unroll
    for (int step = 2048; step >= 1; step >>= 1) {
        int n0 = j0 + step;  n0 = (n0 > TT - 1) ? TT - 1 : n0;
        int n1 = j1 + step;  n1 = (n1 > TT - 1) ? TT - 1 : n1;
        if (sh_xp[n0] <= fq0a) j0 = n0;
        if (sh_xp[n1] <= fq0b) j1 = n1;
    }

    #pragma unroll
    for (int ch = 0; ch < 2; ++ch) {
        const int qbase = (ch == 0) ? q0a : q0b;
        int j = (ch == 0) ? j0 : j1;
        float r[4];
        #pragma unroll
        for (int e = 0; e < 4; ++e) {
            const float fq = (float)(qbase + e);
            while (j < TT - 1 && sh_xp[j + 1] <= fq) ++j;   // monotone walk
            float v;
            if (j < 0) {
                v = sh_fp[0];                                // left clamp
            } else if (j >= TT - 1) {
                v = sh_fp[TT - 1];                           // right clamp
            } else {
                float xa = sh_xp[j], xb = sh_xp[j + 1];
                float fa = sh_fp[j], fb = sh_fp[j + 1];
                float d  = xb - xa;
                v = (d > 0.0f) ? fa + (fq - xa) * (fb - fa) / d : fa;
            }
            r[e] = v;
        }
        float4 res = make_float4(r[0], r[1], r[2], r[3]);
        ((float4*)orow)[tid + ch * NTHR] = res;              // coalesced store
    }
}

extern "C" void kernel_launch(void* const* d_in, const int* in_sizes, int n_in,
                              void* d_out, int out_size, void* d_ws, size_t ws_size,
                              hipStream_t stream) {
    const float* x    = (const float*)d_in[0];   // (64,128,4096) fp32
    const float* yy   = (const float*)d_in[1];   // (64,6,128)    fp32
    const float* mask = (const float*)d_in[2];   // (64,1,1)      fp32
    float* out = (float*)d_out;                  // (64,128,4096) fp32
    timewarp_kernel<<<dim3(BB * CC), dim3(NTHR), 0, stream>>>(x, yy, mask, out);
}

// Round 2
// 231.534 us; speedup vs baseline: 1.0172x; 1.0053x over previous
//
#include <hip/hip_runtime.h>

#define BB 64
#define CC 128
#define TT 4096
#define NN 6            // KNOT + 2
#define HH 819.0f       // (T-1)/(KNOT+1) = 4095/5, exact in fp32
#define NTHR 512
#define EPT 8           // curve elements per thread (NTHR*EPT == TT)

typedef float f4 __attribute__((ext_vector_type(4)));

__device__ __forceinline__ void nt_store4(float* p, f4 v) {
    __builtin_nontemporal_store(v, (f4*)p);
}

// float2-array pad: +1 slot per 32 spreads stride-4 gather reads to the
// 4-way floor (64 lanes x 8B over 32 banks)
__device__ __forceinline__ int p2(int j) { return j + (j >> 5); }
#define ABSZ (4096 + 128 + 1)   // p2(4096) = 4224, need 4225

__global__ __launch_bounds__(NTHR) void timewarp_kernel(
    const float* __restrict__ x,
    const float* __restrict__ yy,
    const float* __restrict__ mask_rand,
    float* __restrict__ out)
{
    const int row = blockIdx.x;          // b*C + c
    const int b   = row / CC;
    const int c   = row % CC;
    const int tid = threadIdx.x;

    const float* xrow = x + (size_t)row * TT;
    float* orow       = out + (size_t)row * TT;

    // mask_rand >= 0.5 -> bit-exact copy (uniform per block)
    if (!(mask_rand[b] < 0.5f)) {
        const f4* xi = (const f4*)xrow;
        nt_store4(orow + 4 * tid,            xi[tid]);
        nt_store4(orow + 4 * (tid + NTHR),   xi[tid + NTHR]);
        return;
    }

    __shared__ float2         sh_ab[ABSZ];   // per-segment line coeffs (a,b), padded
    __shared__ unsigned short sh_jt[TT];     // q -> segment id (4095=head, 4096=tail)
    __shared__ float          sh_xx[NTHR];   // xp boundary exchange
    __shared__ float          sh_fx[NTHR];   // fp boundary exchange
    __shared__ float          sh_wsum[NTHR / 64];

    // ---- load this thread's 8 consecutive x values (L1 absorbs the 32B lane stride) ----
    const int t0 = tid * EPT;
    float fpv[EPT];
    {
        const f4 v0 = *(const f4*)(xrow + t0);
        const f4 v1 = *(const f4*)(xrow + t0 + 4);
        fpv[0] = v0.x; fpv[1] = v0.y; fpv[2] = v0.z; fpv[3] = v0.w;
        fpv[4] = v1.x; fpv[5] = v1.y; fpv[6] = v1.z; fpv[7] = v1.w;
    }
    sh_fx[tid] = fpv[0];                     // boundary exchange (fenced by B1)

    // ---- 6x6 not-a-knot solve, redundantly on every thread ----
    // A is compile-time constant -> elimination multipliers fold to constants;
    // yy addresses are block-uniform -> scalar loads. No barrier needed.
    float Mv[NN];
    float y[NN];
    {
        #pragma unroll
        for (int k = 0; k < NN; ++k)
            y[k] = yy[((size_t)b * NN + k) * CC + c];
        float Aug[NN][NN + 1];
        #pragma unroll
        for (int i = 0; i < NN; ++i)
            #pragma unroll
            for (int j = 0; j < NN + 1; ++j)
                Aug[i][j] = 0.0f;
        Aug[0][0] = 1.0f;  Aug[0][1] = -2.0f;  Aug[0][2] = 1.0f;
        Aug[5][3] = 1.0f;  Aug[5][4] = -2.0f;  Aug[5][5] = 1.0f;
        #pragma unroll
        for (int i = 1; i < NN - 1; ++i) {
            Aug[i][i - 1] = HH / 6.0f;
            Aug[i][i]     = 2.0f * HH / 3.0f;
            Aug[i][i + 1] = HH / 6.0f;
            Aug[i][NN]    = (y[i + 1] - 2.0f * y[i] + y[i - 1]) / HH;
        }
        #pragma unroll
        for (int k = 0; k < NN; ++k) {
            float inv = 1.0f / Aug[k][k];
            #pragma unroll
            for (int i = k + 1; i < NN; ++i) {
                float m = Aug[i][k] * inv;
                #pragma unroll
                for (int j = k; j < NN + 1; ++j)
                    Aug[i][j] -= m * Aug[k][j];
            }
        }
        #pragma unroll
        for (int i = NN - 1; i >= 0; --i) {
            float s = Aug[i][NN];
            #pragma unroll
            for (int j = i + 1; j < NN; ++j)
                s -= Aug[i][j] * Mv[j];
            Mv[i] = s / Aug[i][i];
        }
    }

    // ---- per-thread span Horner coefficients (STATIC register indexing only) ----
    // 8 consecutive t's cross at most one knot boundary (span = 819 >> 8).
    // curve(s) = alpha + s*(beta + s*(gamma + s*delta)), s = t - xl
    int idxA = t0 / 819;  if (idxA > 4) idxA = 4;
    int idxB = idxA + 1;  if (idxB > 4) idxB = 4;
    float MiA = Mv[0], Mi1A = Mv[1], yiA = y[0], yi1A = y[1];
    #pragma unroll
    for (int s = 1; s <= 4; ++s)
        if (idxA >= s) { MiA = Mv[s]; Mi1A = Mv[s + 1]; yiA = y[s]; yi1A = y[s + 1]; }
    float MiB = Mv[0], Mi1B = Mv[1], yiB = y[0], yi1B = y[1];
    #pragma unroll
    for (int s = 1; s <= 4; ++s)
        if (idxB >= s) { MiB = Mv[s]; Mi1B = Mv[s + 1]; yiB = y[s]; yi1B = y[s + 1]; }
    const float invh  = 1.0f / HH;
    const float inv6h = 1.0f / (6.0f * HH);
    const float aA = yiA;
    const float bA = (yi1A - yiA) * invh - MiA * (HH / 3.0f) - Mi1A * (HH / 6.0f);
    const float cA = MiA * 0.5f;
    const float dA = (Mi1A - MiA) * inv6h;
    const float aB = yiB;
    const float bB = (yi1B - yiB) * invh - MiB * (HH / 3.0f) - Mi1B * (HH / 6.0f);
    const float cB = MiB * 0.5f;
    const float dB = (Mi1B - MiB) * inv6h;
    const float xlA = (float)idxA * HH;
    const float xlB = (float)idxB * HH;
    const float tb  = (float)((idxA + 1) * 819);   // first t belonging to span B

    // ---- curve + thread-local inclusive scan ----
    float loc[EPT];
    float running = 0.0f;
    #pragma unroll
    for (int k = 0; k < EPT; ++k) {
        float ft = (float)(t0 + k);
        bool inB = ft >= tb;
        float xl = inB ? xlB : xlA;
        float ca = inB ? aB : aA;
        float cb = inB ? bB : bA;
        float cc = inB ? cB : cA;
        float cd = inB ? dB : dA;
        float s  = ft - xl;
        running += fmaf(s, fmaf(s, fmaf(s, cd, cc), cb), ca);
        loc[k] = running;
    }

    // ---- wave scan (shfl) + cross-wave fixup (barrier 1) ----
    const int lane = tid & 63, wid = tid >> 6;
    float ws = running;
    #pragma unroll
    for (int d = 1; d < 64; d <<= 1) {
        float v = __shfl_up(ws, d, 64);
        if (lane >= d) ws += v;
    }
    if (lane == 63) sh_wsum[wid] = ws;
    __syncthreads();                            // B1
    float wo = 0.0f, total = 0.0f;
    #pragma unroll
    for (int w = 0; w < NTHR / 64; ++w) {
        float s = sh_wsum[w];
        total += s;
        if (w < wid) wo += s;
    }
    const float offs  = wo + (ws - running);    // exclusive prefix of this thread
    const float scale = 4095.0f / total;        // tt * (T-1) / tt_last

    float xpv[EPT + 1];
    #pragma unroll
    for (int k = 0; k < EPT; ++k)
        xpv[k] = (loc[k] + offs) * scale;
    sh_xx[tid] = xpv[0];
    __syncthreads();                            // B2: xp boundary visible
    xpv[EPT]  = (tid < NTHR - 1) ? sh_xx[tid + 1] : 4095.0f;  // tid 511: unused
    const float fpb = (tid < NTHR - 1) ? sh_fx[tid + 1] : fpv[EPT - 1];

    // ---- per-segment line coeffs + inverse-index scatter ----
    // segment j owns q in [ceil(xp[j]), ceil(xp[j+1])-1]; boundaries are
    // bit-exact shared via sh_xx -> telescoping coverage, no gaps.
    #pragma unroll
    for (int k = 0; k < EPT; ++k) {
        int seg = t0 + k;
        if (seg < TT - 1) {
            float xa = xpv[k], xb = xpv[k + 1];
            float fa = fpv[k];
            float fb = (k < EPT - 1) ? fpv[k + 1] : fpb;
            float d  = xb - xa;
            float isl = (d > 0.0f) ? (fb - fa) * __builtin_amdgcn_rcpf(d) : 0.0f;
            sh_ab[p2(seg)] = make_float2(fmaf(-xa, isl, fa), isl);
            int qlo = (int)ceilf(xa);  if (qlo < 0) qlo = 0;
            int qhi = (int)ceilf(xb);  if (qhi > TT) qhi = TT;
            for (int q = qlo; q < qhi; ++q)
                sh_jt[q] = (unsigned short)seg;
        }
    }
    if (tid == 0) {                             // head: q < xp[0] -> fp[0]
        sh_ab[p2(TT - 1)] = make_float2(fpv[0], 0.0f);
        int qh = (int)ceilf(xpv[0]);  if (qh > TT) qh = TT;
        for (int q = 0; q < qh; ++q) sh_jt[q] = (unsigned short)(TT - 1);
    }
    if (tid == NTHR - 1) {                      // tail: q >= xp[4095] -> fp[4095]
        sh_ab[p2(TT)] = make_float2(fpv[EPT - 1], 0.0f);
        int q0 = (int)ceilf(xpv[EPT - 1]);  if (q0 < 0) q0 = 0;
        for (int q = q0; q < TT; ++q) sh_jt[q] = (unsigned short)TT;
    }
    __syncthreads();                            // B3: jtab + ab visible

    // ---- gather: O(1) per output, 2 coalesced float4 chunks per thread ----
    #pragma unroll
    for (int ch = 0; ch < 2; ++ch) {
        const int qb = 4 * tid + ch * (4 * NTHR);
        ushort4 jt = *(const ushort4*)(sh_jt + qb);   // 8B-aligned ds_read_b64
        const float fqb = (float)qb;
        f4 res;
        {
            float2 s0 = sh_ab[p2((int)jt.x)];
            float2 s1 = sh_ab[p2((int)jt.y)];
            float2 s2 = sh_ab[p2((int)jt.z)];
            float2 s3 = sh_ab[p2((int)jt.w)];
            res.x = fmaf(fqb + 0.0f, s0.y, s0.x);
            res.y = fmaf(fqb + 1.0f, s1.y, s1.x);
            res.z = fmaf(fqb + 2.0f, s2.y, s2.x);
            res.w = fmaf(fqb + 3.0f, s3.y, s3.x);
        }
        nt_store4(orow + qb, res);
    }
}

extern "C" void kernel_launch(void* const* d_in, const int* in_sizes, int n_in,
                              void* d_out, int out_size, void* d_ws, size_t ws_size,
                              hipStream_t stream) {
    const float* x    = (const float*)d_in[0];   // (64,128,4096) fp32
    const float* yy   = (const float*)d_in[1];   // (64,6,128)    fp32
    const float* mask = (const float*)d_in[2];   // (64,1,1)      fp32
    float* out = (float*)d_out;                  // (64,128,4096) fp32
    timewarp_kernel<<<dim3(BB * CC), dim3(NTHR), 0, stream>>>(x, yy, mask, out);
}